// Round 8
// baseline (267.155 us; speedup 1.0000x reference)
//
#include <hip/hip_runtime.h>
#include <hip/hip_bf16.h>

#define W_WORDS 2048
#define H_DIM   1024
#define C_LAB   32
#define HID_D   512
#define MAXW    12
#define NSPAN   (W_WORDS * MAXW)

typedef __attribute__((ext_vector_type(8))) short bf16x8;
typedef __attribute__((ext_vector_type(4))) float f32x4;

__device__ __forceinline__ unsigned short f2b(float x) {
  union { float f; unsigned int i; } v; v.f = x;
  unsigned int r = v.i + 0x7FFFu + ((v.i >> 16) & 1u);
  return (unsigned short)(r >> 16);
}
__device__ __forceinline__ float b2f(unsigned short b) {
  union { float f; unsigned int i; } v; v.i = ((unsigned int)b) << 16;
  return v.f;
}

#define GLOAD_LDS16(g, l)                                                    \
  __builtin_amdgcn_global_load_lds(                                          \
      (const __attribute__((address_space(1))) unsigned int*)(g),            \
      (__attribute__((address_space(3))) unsigned int*)(l), 16, 0, 0)

// ---------- gather: we_b[m-1] = bf16(hs[t]) (one token per word) ----------
__global__ void gather_k(const float* __restrict__ hs, const int* __restrict__ wm,
                         unsigned short* __restrict__ we_b) {
  int t = blockIdx.x;
  int m = wm[t];
  if (m <= 0) return;
  const float* src = hs + (size_t)t * H_DIM;
  unsigned short* dst = we_b + (size_t)(m - 1) * H_DIM;
  int i = threadIdx.x * 4;
  float4 v = *(const float4*)(src + i);
  ushort4 o = make_ushort4(f2b(v.x), f2b(v.y), f2b(v.z), f2b(v.w));
  *(ushort4*)(dst + i) = o;
}

// ---------- weight transposes + Wt0 copy-cvt in one launch ----------
__global__ void transpose_all_k(
    const float* __restrict__ Wt, const float* __restrict__ W1a,
    const float* __restrict__ Wsp1, const float* __restrict__ W1c,
    const float* __restrict__ Wsp2,
    unsigned short* __restrict__ WtT, unsigned short* __restrict__ W1aT,
    unsigned short* __restrict__ Wsp1Tc, float* __restrict__ W1cT,
    float* __restrict__ Wsp2T, unsigned short* __restrict__ Wtb0) {
  int c0 = blockIdx.x * 32, r0 = blockIdx.y * 32;
  if (blockIdx.z == 6) {  // straight cvt: Wtb0[h][g] = bf16(Wt[h][g]), g<1024
    if (c0 >= 1024) return;
    for (int i = threadIdx.y; i < 32; i += 8)
      Wtb0[(size_t)(r0 + i) * 1024 + c0 + threadIdx.x] =
          f2b(Wt[(size_t)(r0 + i) * 2048 + c0 + threadIdx.x]);
    return;
  }
  const float* in;
  void* out;
  int R, C, obf;
  switch (blockIdx.z) {
    case 0: in = Wt;   out = WtT;    R = 1024; C = 2048; obf = 1; break;
    case 1: in = W1a;  out = W1aT;   R = 1024; C = 512;  obf = 1; break;
    case 2: in = Wsp1; out = Wsp1Tc; R = 1024; C = 1024; obf = 1; break;
    case 3: in = Wsp1 + 1048576; out = Wsp1Tc + 1048576; R = 1024; C = 1024; obf = 1; break;
    case 4: in = W1c;  out = W1cT;   R = 1024; C = 512;  obf = 0; break;
    default: in = Wsp2; out = Wsp2T; R = 1024; C = 1024; obf = 0; break;
  }
  if (c0 >= C || r0 >= R) return;
  __shared__ float tile[32][33];
  for (int i = threadIdx.y; i < 32; i += 8)
    tile[i][threadIdx.x] = in[(size_t)(r0 + i) * C + c0 + threadIdx.x];
  __syncthreads();
  if (obf) {
    unsigned short* o = (unsigned short*)out;
    for (int i = threadIdx.y; i < 32; i += 8)
      o[(size_t)(c0 + i) * R + r0 + threadIdx.x] = f2b(tile[threadIdx.x][i]);
  } else {
    float* o = (float*)out;
    for (int i = threadIdx.y; i < 32; i += 8)
      o[(size_t)(c0 + i) * R + r0 + threadIdx.x] = tile[threadIdx.x][i];
  }
}

// ---------- small GEMM body, 8 A-rows per block ----------
__device__ __forceinline__ void rgemm8_body(int N, int M,
    const float* __restrict__ A, int lda, const float* __restrict__ B, int ldb,
    const float* __restrict__ bias, float* __restrict__ out, int ldc) {
  __shared__ float Asm[8][1024];
  __shared__ float red[16][16][8];
  int m0 = blockIdx.y * 8;
  for (int idx = threadIdx.x; idx < 8 * 1024; idx += 256) {
    int mm = idx >> 10, kk = idx & 1023;
    Asm[mm][kk] = (m0 + mm < M) ? A[(size_t)(m0 + mm) * lda + kk] : 0.f;
  }
  __syncthreads();
  int tx = threadIdx.x & 15, ty = threadIdx.x >> 4;
  int n = blockIdx.x * 16 + tx;
  float acc[8] = {0.f, 0.f, 0.f, 0.f, 0.f, 0.f, 0.f, 0.f};
  if (n < N) {
    for (int k = ty * 64; k < ty * 64 + 64; ++k) {
      float bv = B[(size_t)k * ldb + n];
#pragma unroll
      for (int mm = 0; mm < 8; ++mm) acc[mm] = fmaf(Asm[mm][k], bv, acc[mm]);
    }
  }
#pragma unroll
  for (int mm = 0; mm < 8; ++mm) red[ty][tx][mm] = acc[mm];
  __syncthreads();
  if (ty < 8 && n < N && m0 + ty < M) {
    float s = 0.f;
#pragma unroll
    for (int q = 0; q < 16; ++q) s += red[q][tx][ty];
    if (bias) s += bias[n];
    out[(size_t)(m0 + ty) * ldc + n] = s;
  }
}

__global__ __launch_bounds__(256) void rgemm8_k(int N, int M,
    const float* __restrict__ A, int lda, const float* __restrict__ B, int ldb,
    const float* __restrict__ bias, float* __restrict__ out, int ldc) {
  rgemm8_body(N, M, A, lda, B, ldb, bias, out, ldc);
}

// lab = L@Wl+bl (z=0) and MmTf = L@Wsp2T (z=1) in one launch
__global__ __launch_bounds__(256) void rgemm8z_k(
    const float* __restrict__ L, const float* __restrict__ Wl,
    const float* __restrict__ bl, float* __restrict__ lab,
    const float* __restrict__ Wsp2T, float* __restrict__ MmTf) {
  if (blockIdx.z == 0) {
    rgemm8_body(2048, 32, L, 1024, Wl, 2048, bl, lab, 2048);
  } else {
    if (blockIdx.x >= 64) return;
    rgemm8_body(1024, 32, L, 1024, Wsp2T, 1024, nullptr, MmTf, 1024);
  }
}

// ---------- misc small ops in one launch ----------
__global__ __launch_bounds__(256) void misc_k(
    const float* __restrict__ bsp2, const float* __restrict__ L,
    float* __restrict__ cv, const float* __restrict__ MmTf,
    unsigned short* __restrict__ MmTb, const float* __restrict__ W2,
    unsigned short* __restrict__ W2padT, const float* __restrict__ bsp1,
    unsigned short* __restrict__ bsp1b, const float* __restrict__ bt,
    const float* __restrict__ W1a, float* __restrict__ bt0A) {
  __shared__ float red[4];
  int b = blockIdx.x;
  if (b < 32) {  // cv[c] = dot(bsp2, L[c])
    int c = b;
    float a = 0.f;
    for (int k = threadIdx.x; k < 1024; k += 256)
      a = fmaf(bsp2[k], L[(size_t)c * 1024 + k], a);
#pragma unroll
    for (int off = 32; off; off >>= 1) a += __shfl_down(a, off);
    if ((threadIdx.x & 63) == 0) red[threadIdx.x >> 6] = a;
    __syncthreads();
    if (threadIdx.x == 0) cv[c] = red[0] + red[1] + red[2] + red[3];
  } else if (b < 64) {  // MmTf -> MmTb bf16
    int i = (b - 32) * 1024 + threadIdx.x * 4;
    float4 v = *(const float4*)(MmTf + i);
    *(ushort4*)(MmTb + i) = make_ushort4(f2b(v.x), f2b(v.y), f2b(v.z), f2b(v.w));
  } else if (b < 96) {  // W2padT[n][d] = n<3 ? W2[d][n] : 0
    int i = (b - 64) * 256 + threadIdx.x;
    int n = i >> 9, d = i & 511;
    W2padT[i] = f2b(n < 3 ? W2[d * 3 + n] : 0.f);
  } else if (b == 96) {  // bsp1 -> bsp1b bf16
    int i = threadIdx.x * 4;
    float4 v = *(const float4*)(bsp1 + i);
    *(ushort4*)(bsp1b + i) = make_ushort4(f2b(v.x), f2b(v.y), f2b(v.z), f2b(v.w));
  } else {  // b = 97,98: bt0A[d] = dot(bt[0:1024], W1a[:,d])
    int d = (b - 97) * 256 + threadIdx.x;
    float a = 0.f;
    for (int k = 0; k < 1024; ++k)
      a = fmaf(bt[k], W1a[(size_t)k * 512 + d], a);
    bt0A[d] = a;
  }
}

// ---------- build K^T[(c*512+d)][h] = l1[c][h] * W1c[h][d], 8 h/thread ----------
__global__ __launch_bounds__(256) void kmat_k(const float* __restrict__ lab,
    const float* __restrict__ W1cT, unsigned short* __restrict__ KT) {
  size_t gid = (size_t)blockIdx.x * 256 + threadIdx.x;  // 2,097,152
  int row = (int)(gid >> 7);
  int h0 = ((int)gid & 127) * 8;
  int c = row >> 9, d = row & 511;
  const float* lp = lab + (size_t)c * 2048 + 1024 + h0;
  const float* wp = W1cT + (size_t)d * 1024 + h0;
  float4 l0 = *(const float4*)lp, l1 = *(const float4*)(lp + 4);
  float4 w0 = *(const float4*)wp, w1 = *(const float4*)(wp + 4);
  bf16x8 o;
  o[0] = (short)f2b(l0.x * w0.x); o[1] = (short)f2b(l0.y * w0.y);
  o[2] = (short)f2b(l0.z * w0.z); o[3] = (short)f2b(l0.w * w0.w);
  o[4] = (short)f2b(l1.x * w1.x); o[5] = (short)f2b(l1.y * w1.y);
  o[6] = (short)f2b(l1.z * w1.z); o[7] = (short)f2b(l1.w * w1.w);
  *(bf16x8*)(KT + (size_t)row * 1024 + h0) = o;
}

// ---------- bf16 MFMA GEMM, 128x128 tile, BK=64, counted-vmcnt dbuf ----------
// MODE 1: merged N=4608: c<2048 tok(+bias)->out0/out1; <4096 -> out2 bf16 (UVb);
//         else Avec f32 = v + bias2[c-4096] -> outF (ld 512)
// MODE 2: 1-D grid, 8x8 supertile XCD order; h=relu(v+avec+bvec)->LDS->W2 MFMA
// MODE 3: out0 bf16 full tile (ld N)
template <int MODE>
__global__ __launch_bounds__(256) void gemm_k(
    const unsigned short* __restrict__ A, const unsigned short* __restrict__ BT,
    int N, int K,
    float* __restrict__ outF,
    unsigned short* __restrict__ out0, unsigned short* __restrict__ out1,
    unsigned short* __restrict__ out2,
    const float* __restrict__ bias, const float* __restrict__ bias2,
    const float* __restrict__ avec, const float* __restrict__ bvec,
    const unsigned short* __restrict__ w2t) {
  __shared__ __align__(16) unsigned short smem[2][16384];  // 64 KB dbuf
  int tid = threadIdx.x;
  int lane = tid & 63, wid = tid >> 6;
  int wr = wid >> 1, wc = wid & 1;
  int row0, col0, cbq = 0;
  if (MODE == 2) {
    // 8 xcd x (2x2 supergrid of 8rb x 8cb supertiles): L2 set = 2MB A + 2MB B
    int bid = blockIdx.x;
    int xcd = bid & 7, i = bid >> 3;
    int sg = i >> 6, inner = i & 63;
    int rb = ((sg >> 1) << 3) | (inner & 7);
    int cb = xcd * 16 + (((sg & 1) << 3) | (inner >> 3));
    row0 = rb * 128; col0 = cb * 128; cbq = cb & 3;
  } else {
    row0 = blockIdx.y * 128; col0 = blockIdx.x * 128;
  }

  f32x4 zero4 = {0.f, 0.f, 0.f, 0.f};
  f32x4 acc[4][4];
#pragma unroll
  for (int i = 0; i < 4; ++i)
#pragma unroll
    for (int j = 0; j < 4; ++j) acc[i][j] = zero4;

  // staging: row = i2*32 + tid>>3, phys slot = tid&7, pre-swizzled source
  int srow = tid >> 3;
  int scol = ((tid & 7) ^ (srow & 7)) * 8;
  const unsigned short* gA = A + (size_t)(row0 + srow) * K + scol;
  const unsigned short* gB = BT + (size_t)(col0 + srow) * K + scol;

  int fr = lane & 15, hi = lane >> 4;

#define G_STAGE(buf, kt)                                                     \
  {                                                                          \
    unsigned short* dA = smem[buf] + tid * 8;                                \
    unsigned short* dB = smem[buf] + 8192 + tid * 8;                         \
    _Pragma("unroll")                                                        \
    for (int i2 = 0; i2 < 4; ++i2) {                                         \
      GLOAD_LDS16(gA + (size_t)(i2 * 32) * K + (kt), dA + i2 * 2048);        \
      GLOAD_LDS16(gB + (size_t)(i2 * 32) * K + (kt), dB + i2 * 2048);        \
    }                                                                        \
  }

  G_STAGE(0, 0);  // prologue: tile 0 -> buf 0 (8 loads in flight)

  int nt = K >> 6;
  for (int t = 0; t < nt; ++t) {
    if (t + 1 < nt) {
      G_STAGE((t + 1) & 1, (t + 1) << 6);  // 8 more loads; 16 outstanding
      asm volatile("s_waitcnt vmcnt(8)" ::: "memory");  // tile t retired, t+1 in flight
    } else {
      asm volatile("s_waitcnt vmcnt(0)" ::: "memory");
    }
    __builtin_amdgcn_sched_barrier(0);
    __builtin_amdgcn_s_barrier();  // all waves confirmed own tile-t loads
    __builtin_amdgcn_sched_barrier(0);

    const unsigned short* As = smem[t & 1];
    const unsigned short* Bs = smem[t & 1] + 8192;
    bf16x8 af[4][2], bfr[4][2];
#pragma unroll
    for (int mi = 0; mi < 4; ++mi) {
      int rl = wr * 64 + mi * 16 + fr;
#pragma unroll
      for (int kk = 0; kk < 2; ++kk)
        af[mi][kk] = *(const bf16x8*)&As[rl * 64 + (((kk << 2) | hi) ^ (rl & 7)) * 8];
    }
#pragma unroll
    for (int ni = 0; ni < 4; ++ni) {
      int rl = wc * 64 + ni * 16 + fr;
#pragma unroll
      for (int kk = 0; kk < 2; ++kk)
        bfr[ni][kk] = *(const bf16x8*)&Bs[rl * 64 + (((kk << 2) | hi) ^ (rl & 7)) * 8];
    }
#pragma unroll
    for (int kk = 0; kk < 2; ++kk)
#pragma unroll
      for (int mi = 0; mi < 4; ++mi)
#pragma unroll
        for (int ni = 0; ni < 4; ++ni)
          acc[mi][ni] = __builtin_amdgcn_mfma_f32_16x16x32_bf16(af[mi][kk], bfr[ni][kk],
                                                                acc[mi][ni], 0, 0, 0);
    __builtin_amdgcn_sched_barrier(0);
    __builtin_amdgcn_s_barrier();  // reads of buf[t] done -> next iter may overwrite
  }
#undef G_STAGE

  // C/D layout: col = lane&15, row = (lane>>4)*4 + j  [m89-verified]
  if (MODE == 2) {
    unsigned short* hsm = &smem[0][0];  // 32 KB h tile
    int cc = col0 >> 9;
    int dg0 = col0 & 511;
#pragma unroll
    for (int mi = 0; mi < 4; ++mi) {
#pragma unroll
      for (int j = 0; j < 4; ++j) {
        int rl = wr * 64 + hi * 4 + mi * 16 + j;
        const float* avp = avec + (size_t)(row0 + rl) * 512 + dg0;
        const float* bvp = bvec + (size_t)cc * 512 + dg0;
#pragma unroll
        for (int ni = 0; ni < 4; ++ni) {
          int cl = wc * 64 + ni * 16 + fr;
          float v = acc[mi][ni][j] + avp[cl] + bvp[cl];
          v = fmaxf(v, 0.f);
          int slot = cl >> 3;
          hsm[rl * 128 + (((slot ^ rl) & 7) << 3) + (slot & 8) * 8 + (cl & 7)] = f2b(v);
        }
      }
    }
    __syncthreads();
    f32x4 s0 = zero4, s1 = zero4;
    int r0l = wid * 32 + fr;
    int r1l = wid * 32 + 16 + fr;
#pragma unroll
    for (int kt2 = 0; kt2 < 4; ++kt2) {
      int slot = kt2 * 4 + hi;
      bf16x8 a0 = *(const bf16x8*)&hsm[r0l * 128 + (((slot ^ r0l) & 7) << 3) + (slot & 8) * 8];
      bf16x8 a1 = *(const bf16x8*)&hsm[r1l * 128 + (((slot ^ r1l) & 7) << 3) + (slot & 8) * 8];
      bf16x8 b = *(const bf16x8*)&w2t[(size_t)fr * 512 + dg0 + kt2 * 32 + hi * 8];
      s0 = __builtin_amdgcn_mfma_f32_16x16x32_bf16(a0, b, s0, 0, 0, 0);
      s1 = __builtin_amdgcn_mfma_f32_16x16x32_bf16(a1, b, s1, 0, 0, 0);
    }
    if (fr < 3) {
      float* sp = outF + ((size_t)cbq * 2048 + row0) * 96 + cc * 3 + fr;
#pragma unroll
      for (int j = 0; j < 4; ++j) {
        sp[(size_t)(wid * 32 + hi * 4 + j) * 96] = s0[j];
        sp[(size_t)(wid * 32 + 16 + hi * 4 + j) * 96] = s1[j];
      }
    }
    return;
  }

  int rbase = row0 + wr * 64 + (hi << 2);
  int cbase = col0 + wc * 64 + fr;
#pragma unroll
  for (int mi = 0; mi < 4; ++mi) {
#pragma unroll
    for (int ni = 0; ni < 4; ++ni) {
      int ccol = cbase + ni * 16;
#pragma unroll
      for (int j = 0; j < 4; ++j) {
        int r = rbase + mi * 16 + j;
        float v = acc[mi][ni][j];
        if (MODE == 3) {
          out0[(size_t)r * N + ccol] = f2b(v);
        } else {
          if (ccol < 2048) {
            v += bias[ccol];
            if (ccol < 1024) out0[(size_t)r * 1024 + ccol] = f2b(v);
            else             out1[(size_t)r * 1024 + (ccol - 1024)] = f2b(v);
          } else if (ccol < 4096) {
            out2[(size_t)r * 2048 + (ccol - 2048)] = f2b(v);
          } else {
            outF[(size_t)r * 512 + (ccol - 4096)] = v + bias2[ccol - 4096];
          }
        }
      }
    }
  }
}

// ---------- fold 4 score slices + b2 ----------
__global__ void foldscores_k(const float* __restrict__ part, const float* __restrict__ b2,
                             float* __restrict__ outS) {
  int i = blockIdx.x * 256 + threadIdx.x;  // 196608
  float s = b2[i % 3];
  s += part[i] + part[196608 + i] + part[2 * 196608 + i] + part[3 * 196608 + i];
  outS[i] = s;
}

// ---------- is_start / is_end  (sigmoid(x)>=0.5 <=> x>=0) ----------
__global__ void mask_k(const float* __restrict__ scores, int* __restrict__ is_s,
                       int* __restrict__ is_e) {
  int w = blockIdx.x * blockDim.x + threadIdx.x;
  if (w >= W_WORDS) return;
  int s = 0, e = 0;
  for (int c = 0; c < C_LAB; ++c) {
    s |= (scores[((size_t)w * 32 + c) * 3 + 0] >= 0.f);
    e |= (scores[((size_t)w * 32 + c) * 3 + 1] >= 0.f);
  }
  is_s[w] = s;
  is_e[w] = e;
}

// ---------- fused span: 16 spans/wave, barrier-free, bf16 UV ----------
__global__ __launch_bounds__(256) void spanfuse_k(
    const unsigned short* __restrict__ UVb, const unsigned short* __restrict__ bsp1b,
    const unsigned short* __restrict__ MmTb, const float* __restrict__ cvv,
    const int* __restrict__ is_s, const int* __restrict__ is_e,
    float* __restrict__ outIdx, float* __restrict__ outMask,
    float* __restrict__ outLog) {
  __shared__ __align__(16) unsigned short Rs[4][16][32];  // 4 KB, wave-local tiles
  int tid = threadIdx.x, lane = tid & 63, w = tid >> 6;
  int fr = lane & 15, hi = lane >> 4;
  int row = lane >> 2, q = lane & 3;
  int n = blockIdx.x * 64 + w * 16 + row;
  int wi = n / MAXW;
  int j = n - wi * MAXW;
  int er = wi + j;
  int valid = er < W_WORDS;
  int e = valid ? er : (W_WORDS - 1);
  int mask = (valid && is_s[wi] && is_e[e]) ? 1 : 0;
  if (q == 0) {
    outIdx[2 * n] = (float)wi;
    outIdx[2 * n + 1] = (float)e;
    outMask[n] = (float)mask;
  }
  int si = mask ? wi : 0, ei = mask ? e : 0;
  const unsigned short* Up = UVb + (size_t)si * 2048 + q * 8;
  const unsigned short* Vp = UVb + (size_t)ei * 2048 + 1024 + q * 8;
  const unsigned short* bp = bsp1b + q * 8;
  unsigned short* wRs = &Rs[w][0][0];
  f32x4 zero4 = {0.f, 0.f, 0.f, 0.f};
  f32x4 a0 = zero4, a1 = zero4;

  bf16x8 u = *(const bf16x8*)Up;
  bf16x8 v = *(const bf16x8*)Vp;
  bf16x8 bb = *(const bf16x8*)bp;
  bf16x8 fb0 = *(const bf16x8*)&MmTb[(size_t)fr * 1024 + hi * 8];
  bf16x8 fb1 = *(const bf16x8*)&MmTb[(size_t)(16 + fr) * 1024 + hi * 8];

  for (int kt = 0; kt < 32; ++kt) {
    int kn = ((kt + 1) & 31) * 32;
    bf16x8 un = *(const bf16x8*)(Up + kn);
    bf16x8 vn = *(const bf16x8*)(Vp + kn);
    bf16x8 bn = *(const bf16x8*)(bp + kn);
    bf16x8 f0n = *(const bf16x8*)&MmTb[(size_t)fr * 1024 + kn + hi * 8];
    bf16x8 f1n = *(const bf16x8*)&MmTb[(size_t)(16 + fr) * 1024 + kn + hi * 8];

    bf16x8 o;
#pragma unroll
    for (int i = 0; i < 8; ++i) {
      float s = b2f((unsigned short)u[i]) + b2f((unsigned short)v[i]) +
                b2f((unsigned short)bb[i]);
      o[i] = (short)f2b(fmaxf(s, 0.f));
    }
    *(bf16x8*)&wRs[row * 32 + (q ^ (row & 3)) * 8] = o;
    asm volatile("s_waitcnt lgkmcnt(0)" ::: "memory");
    bf16x8 fa = *(const bf16x8*)&wRs[fr * 32 + ((hi ^ (fr & 3)) & 3) * 8];
    a0 = __builtin_amdgcn_mfma_f32_16x16x32_bf16(fa, fb0, a0, 0, 0, 0);
    a1 = __builtin_amdgcn_mfma_f32_16x16x32_bf16(fa, fb1, a1, 0, 0, 0);
    u = un; v = vn; bb = bn; fb0 = f0n; fb1 = f1n;
  }

  int n0 = blockIdx.x * 64 + w * 16;
  float c0 = cvv[fr], c1 = cvv[16 + fr];
#pragma unroll
  for (int jj = 0; jj < 4; ++jj) {
    int nn = n0 + hi * 4 + jj;
    outLog[(size_t)nn * 32 + fr] = a0[jj] + c0;
    outLog[(size_t)nn * 32 + 16 + fr] = a1[jj] + c1;
  }
}

extern "C" void kernel_launch(void* const* d_in, const int* in_sizes, int n_in,
                              void* d_out, int out_size, void* d_ws, size_t ws_size,
                              hipStream_t stream) {
  const float* hs   = (const float*)d_in[0];
  const int*   wm   = (const int*)d_in[1];
  const float* L    = (const float*)d_in[2];
  const float* Wt   = (const float*)d_in[3];
  const float* bt   = (const float*)d_in[4];
  const float* Wl   = (const float*)d_in[5];
  const float* bl   = (const float*)d_in[6];
  const float* W1a  = (const float*)d_in[7];
  const float* W1b  = (const float*)d_in[8];
  const float* W1c  = (const float*)d_in[9];
  const float* b1   = (const float*)d_in[10];
  const float* W2   = (const float*)d_in[11];
  const float* b2   = (const float*)d_in[12];
  const float* Wsp1 = (const float*)d_in[13];
  const float* bsp1 = (const float*)d_in[14];
  const float* Wsp2 = (const float*)d_in[15];
  const float* bsp2 = (const float*)d_in[16];

  char* p = (char*)d_ws;
  auto alloc = [&p](size_t bytes) {
    char* r = p;
    p += (bytes + 255) & ~(size_t)255;
    return r;
  };
  unsigned short* we_b   = (unsigned short*)alloc((size_t)2048 * 1024 * 2);
  // WtT, Wsp1Tc, WfuseT MUST be adjacent: merged BT (4608 x 1024)
  unsigned short* WtT    = (unsigned short*)alloc((size_t)2048 * 1024 * 2);
  unsigned short* Wsp1Tc = (unsigned short*)alloc((size_t)2048 * 1024 * 2);
  unsigned short* WfuseT = (unsigned short*)alloc((size_t)512 * 1024 * 2);
  unsigned short* t0b    = (unsigned short*)alloc((size_t)2048 * 1024 * 2);
  unsigned short* t1b    = (unsigned short*)alloc((size_t)2048 * 1024 * 2);
  float*          lab    = (float*)alloc((size_t)32 * 2048 * 4);
  unsigned short* W1aT   = (unsigned short*)alloc((size_t)512 * 1024 * 2);
  unsigned short* Wtb0   = (unsigned short*)alloc((size_t)1024 * 1024 * 2);
  float*          Avec   = (float*)alloc((size_t)2048 * 512 * 4);
  float*          BvecB  = (float*)alloc((size_t)32 * 512 * 4);
  float*          bt0A   = (float*)alloc(512 * 4);
  float*          W1cT   = (float*)alloc((size_t)512 * 1024 * 4);
  unsigned short* KmatT  = (unsigned short*)alloc((size_t)16384 * 1024 * 2);
  float*          sPart  = (float*)alloc((size_t)4 * 2048 * 96 * 4);
  int*            is_s   = (int*)alloc(2048 * 4);
  int*            is_e   = (int*)alloc(2048 * 4);
  unsigned short* UVb    = (unsigned short*)alloc((size_t)2048 * 2048 * 2);
  float*          Wsp2T  = (float*)alloc((size_t)1024 * 1024 * 4);
  float*          MmTf   = (float*)alloc((size_t)32 * 1024 * 4);
  unsigned short* MmTb   = (unsigned short*)alloc((size_t)32 * 1024 * 2);
  float*          cv     = (float*)alloc(32 * 4);
  unsigned short* W2padT = (unsigned short*)alloc((size_t)16 * 512 * 2);
  unsigned short* bsp1b  = (unsigned short*)alloc((size_t)1024 * 2);

  float* outS    = (float*)d_out;
  float* outIdx  = outS + (size_t)2048 * 32 * 3;
  float* outMask = outIdx + (size_t)NSPAN * 2;
  float* outLog  = outMask + NSPAN;

  gather_k<<<3072, 256, 0, stream>>>(hs, wm, we_b);

  transpose_all_k<<<dim3(64, 32, 7), dim3(32, 8), 0, stream>>>(
      Wt, W1a, Wsp1, W1c, Wsp2, WtT, W1aT, Wsp1Tc, W1cT, Wsp2T, Wtb0);

  // lab = L@Wl+bl and MmTf = L@Wsp2T in one launch
  rgemm8z_k<<<dim3(128, 4, 2), 256, 0, stream>>>(L, Wl, bl, lab, Wsp2T, MmTf);
  // BvecB = l0 @ W1b + b1   (32 x 512)
  rgemm8_k<<<dim3(32, 4), 256, 0, stream>>>(512, 32, lab, 2048, W1b, 512, b1, BvecB, 512);
  // cv, MmTb, W2padT, bsp1b, bt0A in one launch
  misc_k<<<99, 256, 0, stream>>>(bsp2, L, cv, MmTf, MmTb, W2, W2padT, bsp1, bsp1b,
                                 bt, W1a, bt0A);

  // KmatT[(c,d)][h] = l1[c][h] * W1c[h][d]
  kmat_k<<<8192, 256, 0, stream>>>(lab, W1cT, KmatT);

  // WfuseT = W1aT @ Wt0^T  (512 x 1024 bf16): Avec folding matrix
  gemm_k<3><<<dim3(8, 4), 256, 0, stream>>>(W1aT, Wtb0, 1024, 1024, nullptr, WfuseT,
                                            nullptr, nullptr, nullptr, nullptr,
                                            nullptr, nullptr, nullptr);
  // merged: [tok | UV | Avec] = we @ [Wt | Wsp1 | Wfuse]  (N = 4608)
  gemm_k<1><<<dim3(36, 16), 256, 0, stream>>>(we_b, WtT, 4608, 1024, Avec, t0b, t1b,
                                              UVb, bt, bt0A, nullptr, nullptr, nullptr);
  // E-GEMM + fused score partials
  gemm_k<2><<<2048, 256, 0, stream>>>(t1b, KmatT, 16384, 1024, sPart, nullptr, nullptr,
                                      nullptr, nullptr, nullptr, Avec, BvecB, W2padT);
  foldscores_k<<<768, 256, 0, stream>>>(sPart, b2, outS);
  mask_k<<<8, 256, 0, stream>>>(outS, is_s, is_e);

  // fused span: 16 spans/wave, barrier-free
  spanfuse_k<<<384, 256, 0, stream>>>(UVb, bsp1b, MmTb, cv, is_s, is_e,
                                      outIdx, outMask, outLog);
}

// Round 9
// 251.648 us; speedup vs baseline: 1.0616x; 1.0616x over previous
//
#include <hip/hip_runtime.h>
#include <hip/hip_bf16.h>

#define W_WORDS 2048
#define H_DIM   1024
#define C_LAB   32
#define HID_D   512
#define MAXW    12
#define NSPAN   (W_WORDS * MAXW)

typedef __attribute__((ext_vector_type(8))) short bf16x8;
typedef __attribute__((ext_vector_type(4))) float f32x4;

__device__ __forceinline__ unsigned short f2b(float x) {
  union { float f; unsigned int i; } v; v.f = x;
  unsigned int r = v.i + 0x7FFFu + ((v.i >> 16) & 1u);
  return (unsigned short)(r >> 16);
}
__device__ __forceinline__ float b2f(unsigned short b) {
  union { float f; unsigned int i; } v; v.i = ((unsigned int)b) << 16;
  return v.f;
}

#define GLOAD_LDS16(g, l)                                                    \
  __builtin_amdgcn_global_load_lds(                                          \
      (const __attribute__((address_space(1))) unsigned int*)(g),            \
      (__attribute__((address_space(3))) unsigned int*)(l), 16, 0, 0)

// ---------- mega0: 6 weight transposes (z<6) + token gather (z==6) ----------
__global__ void mega0_k(const float* __restrict__ hs, const int* __restrict__ wm,
    unsigned short* __restrict__ we_b,
    const float* __restrict__ Wt, const float* __restrict__ W1a,
    const float* __restrict__ Wsp1, const float* __restrict__ W1c,
    const float* __restrict__ Wsp2,
    unsigned short* __restrict__ WtT, unsigned short* __restrict__ W1aT,
    unsigned short* __restrict__ Wsp1Tc, float* __restrict__ W1cT,
    float* __restrict__ Wsp2T) {
  if (blockIdx.z == 6) {  // gather: we_b[m-1] = bf16(hs[t]) (one token per word)
    int t = blockIdx.y * 96 + blockIdx.x;
    int m = wm[t];
    if (m <= 0) return;
    const float* src = hs + (size_t)t * H_DIM;
    unsigned short* dst = we_b + (size_t)(m - 1) * H_DIM;
    int i = (threadIdx.y * 32 + threadIdx.x) * 4;
    float4 v = *(const float4*)(src + i);
    *(ushort4*)(dst + i) = make_ushort4(f2b(v.x), f2b(v.y), f2b(v.z), f2b(v.w));
    return;
  }
  const float* in;
  void* out;
  int R, C, obf;
  switch (blockIdx.z) {
    case 0: in = Wt;   out = WtT;    R = 1024; C = 2048; obf = 1; break;
    case 1: in = W1a;  out = W1aT;   R = 1024; C = 512;  obf = 1; break;
    case 2: in = Wsp1; out = Wsp1Tc; R = 1024; C = 1024; obf = 1; break;
    case 3: in = Wsp1 + 1048576; out = Wsp1Tc + 1048576; R = 1024; C = 1024; obf = 1; break;
    case 4: in = W1c;  out = W1cT;   R = 1024; C = 512;  obf = 0; break;
    default: in = Wsp2; out = Wsp2T; R = 1024; C = 1024; obf = 0; break;
  }
  int c0 = blockIdx.x * 32, r0 = blockIdx.y * 32;
  if (c0 >= C || r0 >= R) return;
  __shared__ float tile[32][33];
  for (int i = threadIdx.y; i < 32; i += 8)
    tile[i][threadIdx.x] = in[(size_t)(r0 + i) * C + c0 + threadIdx.x];
  __syncthreads();
  if (obf) {
    unsigned short* o = (unsigned short*)out;
    for (int i = threadIdx.y; i < 32; i += 8)
      o[(size_t)(c0 + i) * R + r0 + threadIdx.x] = f2b(tile[threadIdx.x][i]);
  } else {
    float* o = (float*)out;
    for (int i = threadIdx.y; i < 32; i += 8)
      o[(size_t)(c0 + i) * R + r0 + threadIdx.x] = tile[threadIdx.x][i];
  }
}

// ---------- small GEMM body, 8 A-rows per block (explicit block coords) ----------
__device__ __forceinline__ void rgemm8_body(int N, int M,
    const float* __restrict__ A, int lda, const float* __restrict__ B, int ldb,
    const float* __restrict__ bias, float* __restrict__ out, int ldc,
    int bx, int by, float* shf) {
  float (*Asm)[1024] = (float(*)[1024])shf;
  float (*red)[16][8] = (float(*)[16][8])(shf + 8192);
  int m0 = by * 8;
  for (int idx = threadIdx.x; idx < 8 * 1024; idx += 256) {
    int mm = idx >> 10, kk = idx & 1023;
    Asm[mm][kk] = (m0 + mm < M) ? A[(size_t)(m0 + mm) * lda + kk] : 0.f;
  }
  __syncthreads();
  int tx = threadIdx.x & 15, ty = threadIdx.x >> 4;
  int n = bx * 16 + tx;
  float acc[8] = {0.f, 0.f, 0.f, 0.f, 0.f, 0.f, 0.f, 0.f};
  if (n < N) {
    for (int k = ty * 64; k < ty * 64 + 64; ++k) {
      float bv = B[(size_t)k * ldb + n];
#pragma unroll
      for (int mm = 0; mm < 8; ++mm) acc[mm] = fmaf(Asm[mm][k], bv, acc[mm]);
    }
  }
#pragma unroll
  for (int mm = 0; mm < 8; ++mm) red[ty][tx][mm] = acc[mm];
  __syncthreads();
  if (ty < 8 && n < N && m0 + ty < M) {
    float s = 0.f;
#pragma unroll
    for (int q = 0; q < 16; ++q) s += red[q][tx][ty];
    if (bias) s += bias[n];
    out[(size_t)(m0 + ty) * ldc + n] = s;
  }
}

// lab = L@Wl+bl (z=0) and MmTf = L@Wsp2T (z=1) in one launch
__global__ __launch_bounds__(256) void rgemm8z_k(
    const float* __restrict__ L, const float* __restrict__ Wl,
    const float* __restrict__ bl, float* __restrict__ lab,
    const float* __restrict__ Wsp2T, float* __restrict__ MmTf) {
  __shared__ float shf[10240];
  if (blockIdx.z == 0) {
    rgemm8_body(2048, 32, L, 1024, Wl, 2048, bl, lab, 2048, blockIdx.x, blockIdx.y, shf);
  } else {
    if (blockIdx.x >= 64) return;
    rgemm8_body(1024, 32, L, 1024, Wsp2T, 1024, nullptr, MmTf, 1024,
                blockIdx.x, blockIdx.y, shf);
  }
}

// ---------- mega1: kmat (g<8192) + BvecB rgemm8 (g<8320) + misc (g<8417) ----------
__global__ __launch_bounds__(256) void mega1_k(
    const float* __restrict__ lab, const float* __restrict__ W1cT,
    unsigned short* __restrict__ KT,
    const float* __restrict__ W1b, const float* __restrict__ b1,
    float* __restrict__ BvecB,
    const float* __restrict__ bsp2, const float* __restrict__ L,
    float* __restrict__ cv, const float* __restrict__ MmTf,
    unsigned short* __restrict__ MmTb, const float* __restrict__ W2,
    unsigned short* __restrict__ W2padT, const float* __restrict__ bsp1,
    unsigned short* __restrict__ bsp1b) {
  __shared__ float shf[10240];
  int g = blockIdx.x;
  if (g < 8192) {  // KT[(c*512+d)][h] = l1[c][h] * W1c[h][d], 8 h/thread
    size_t gid = (size_t)g * 256 + threadIdx.x;
    int row = (int)(gid >> 7);
    int h0 = ((int)gid & 127) * 8;
    int c = row >> 9, d = row & 511;
    const float* lp = lab + (size_t)c * 2048 + 1024 + h0;
    const float* wp = W1cT + (size_t)d * 1024 + h0;
    float4 l0 = *(const float4*)lp, l1 = *(const float4*)(lp + 4);
    float4 w0 = *(const float4*)wp, w1 = *(const float4*)(wp + 4);
    bf16x8 o;
    o[0] = (short)f2b(l0.x * w0.x); o[1] = (short)f2b(l0.y * w0.y);
    o[2] = (short)f2b(l0.z * w0.z); o[3] = (short)f2b(l0.w * w0.w);
    o[4] = (short)f2b(l1.x * w1.x); o[5] = (short)f2b(l1.y * w1.y);
    o[6] = (short)f2b(l1.z * w1.z); o[7] = (short)f2b(l1.w * w1.w);
    *(bf16x8*)(KT + (size_t)row * 1024 + h0) = o;
  } else if (g < 8320) {  // BvecB = l0 @ W1b + b1   (32 x 512)
    int b = g - 8192;
    rgemm8_body(512, 32, lab, 2048, W1b, 512, b1, BvecB, 512, b & 31, b >> 5, shf);
  } else {
    int b = g - 8320;
    if (b < 32) {  // cv[c] = dot(bsp2, L[c])
      int c = b;
      float a = 0.f;
      for (int k = threadIdx.x; k < 1024; k += 256)
        a = fmaf(bsp2[k], L[(size_t)c * 1024 + k], a);
#pragma unroll
      for (int off = 32; off; off >>= 1) a += __shfl_down(a, off);
      if ((threadIdx.x & 63) == 0) shf[threadIdx.x >> 6] = a;
      __syncthreads();
      if (threadIdx.x == 0) cv[c] = shf[0] + shf[1] + shf[2] + shf[3];
    } else if (b < 64) {  // MmTf -> MmTb bf16
      int i = (b - 32) * 1024 + threadIdx.x * 4;
      float4 v = *(const float4*)(MmTf + i);
      *(ushort4*)(MmTb + i) = make_ushort4(f2b(v.x), f2b(v.y), f2b(v.z), f2b(v.w));
    } else if (b < 96) {  // W2padT[n][d] = n<3 ? W2[d][n] : 0
      int i = (b - 64) * 256 + threadIdx.x;
      int n = i >> 9, d = i & 511;
      W2padT[i] = f2b(n < 3 ? W2[d * 3 + n] : 0.f);
    } else {  // bsp1 -> bsp1b bf16
      int i = threadIdx.x * 4;
      float4 v = *(const float4*)(bsp1 + i);
      *(ushort4*)(bsp1b + i) = make_ushort4(f2b(v.x), f2b(v.y), f2b(v.z), f2b(v.w));
    }
  }
}

// ---------- bf16 MFMA GEMM, 128x128 tile, BK=64, counted-vmcnt dbuf ----------
// MODE 0: outF[r*N+c] = val (f32; Avec N=512)
// MODE 1: c<1024 -> out0; <2048 -> out1 (both +bias); else out2 bf16 (UVb ld2048)
template <int MODE>
__global__ __launch_bounds__(256) void gemm_k(
    const unsigned short* __restrict__ A, const unsigned short* __restrict__ BT,
    int N, int K,
    float* __restrict__ outF,
    unsigned short* __restrict__ out0, unsigned short* __restrict__ out1,
    unsigned short* __restrict__ out2,
    const float* __restrict__ bias) {
  __shared__ __align__(16) unsigned short smem[2][16384];  // 64 KB dbuf
  int tid = threadIdx.x;
  int lane = tid & 63, wid = tid >> 6;
  int wr = wid >> 1, wc = wid & 1;
  int row0 = blockIdx.y * 128, col0 = blockIdx.x * 128;

  f32x4 zero4 = {0.f, 0.f, 0.f, 0.f};
  f32x4 acc[4][4];
#pragma unroll
  for (int i = 0; i < 4; ++i)
#pragma unroll
    for (int j = 0; j < 4; ++j) acc[i][j] = zero4;

  int srow = tid >> 3;
  int scol = ((tid & 7) ^ (srow & 7)) * 8;  // pre-swizzled global source
  const unsigned short* gA = A + (size_t)(row0 + srow) * K + scol;
  const unsigned short* gB = BT + (size_t)(col0 + srow) * K + scol;

  int fr = lane & 15, hi = lane >> 4;

#define G_STAGE(buf, kt)                                                     \
  {                                                                          \
    unsigned short* dA = smem[buf] + tid * 8;                                \
    unsigned short* dB = smem[buf] + 8192 + tid * 8;                         \
    _Pragma("unroll")                                                        \
    for (int i2 = 0; i2 < 4; ++i2) {                                         \
      GLOAD_LDS16(gA + (size_t)(i2 * 32) * K + (kt), dA + i2 * 2048);        \
      GLOAD_LDS16(gB + (size_t)(i2 * 32) * K + (kt), dB + i2 * 2048);        \
    }                                                                        \
  }

  G_STAGE(0, 0);

  int nt = K >> 6;
  for (int t = 0; t < nt; ++t) {
    if (t + 1 < nt) {
      G_STAGE((t + 1) & 1, (t + 1) << 6);
      asm volatile("s_waitcnt vmcnt(8)" ::: "memory");
    } else {
      asm volatile("s_waitcnt vmcnt(0)" ::: "memory");
    }
    __builtin_amdgcn_sched_barrier(0);
    __builtin_amdgcn_s_barrier();
    __builtin_amdgcn_sched_barrier(0);

    const unsigned short* As = smem[t & 1];
    const unsigned short* Bs = smem[t & 1] + 8192;
    bf16x8 af[4][2], bfr[4][2];
#pragma unroll
    for (int mi = 0; mi < 4; ++mi) {
      int rl = wr * 64 + mi * 16 + fr;
#pragma unroll
      for (int kk = 0; kk < 2; ++kk)
        af[mi][kk] = *(const bf16x8*)&As[rl * 64 + (((kk << 2) | hi) ^ (rl & 7)) * 8];
    }
#pragma unroll
    for (int ni = 0; ni < 4; ++ni) {
      int rl = wc * 64 + ni * 16 + fr;
#pragma unroll
      for (int kk = 0; kk < 2; ++kk)
        bfr[ni][kk] = *(const bf16x8*)&Bs[rl * 64 + (((kk << 2) | hi) ^ (rl & 7)) * 8];
    }
#pragma unroll
    for (int kk = 0; kk < 2; ++kk)
#pragma unroll
      for (int mi = 0; mi < 4; ++mi)
#pragma unroll
        for (int ni = 0; ni < 4; ++ni)
          acc[mi][ni] = __builtin_amdgcn_mfma_f32_16x16x32_bf16(af[mi][kk], bfr[ni][kk],
                                                                acc[mi][ni], 0, 0, 0);
    __builtin_amdgcn_sched_barrier(0);
    __builtin_amdgcn_s_barrier();
  }
#undef G_STAGE

  int rbase = row0 + wr * 64 + (hi << 2);
  int cbase = col0 + wc * 64 + fr;
#pragma unroll
  for (int mi = 0; mi < 4; ++mi) {
#pragma unroll
    for (int ni = 0; ni < 4; ++ni) {
      int ccol = cbase + ni * 16;
#pragma unroll
      for (int j = 0; j < 4; ++j) {
        int r = rbase + mi * 16 + j;
        float v = acc[mi][ni][j];
        if (MODE == 0) {
          outF[(size_t)r * N + ccol] = v;
        } else {
          if (ccol < 2048) {
            v += bias[ccol];
            if (ccol < 1024) out0[(size_t)r * 1024 + ccol] = f2b(v);
            else             out1[(size_t)r * 1024 + (ccol - 1024)] = f2b(v);
          } else {
            out2[(size_t)r * 2048 + (ccol - 2048)] = f2b(v);
          }
        }
      }
    }
  }
}

// ---------- E-GEMM: 128x128 tile, BK=32, 32KB LDS dbuf (5 blocks/CU) ----------
// h = relu(gemm + avec + bvec) -> swizzled LDS -> MFMA vs W2padT -> sPart slice.
__global__ __launch_bounds__(256) void egemm_k(
    const unsigned short* __restrict__ A,   // t1b [2048][1024]
    const unsigned short* __restrict__ BT,  // KmatT [16384][1024]
    const float* __restrict__ avec, const float* __restrict__ bvec,
    const unsigned short* __restrict__ w2t, float* __restrict__ sPart) {
  __shared__ __align__(16) unsigned short smem[2][8192];  // 2 x 16KB (A 8KB | B 8KB)
  int tid = threadIdx.x;
  int lane = tid & 63, wid = tid >> 6;
  int wr = wid >> 1, wc = wid & 1;
  // 8 xcd x (2x2 supergrid of 8rb x 8cb supertiles): L2 set = 2MB A + 2MB B
  int bid = blockIdx.x;
  int xcd = bid & 7, ii = bid >> 3;
  int sg = ii >> 6, inner = ii & 63;
  int rb = ((sg >> 1) << 3) | (inner & 7);
  int cb = xcd * 16 + (((sg & 1) << 3) | (inner >> 3));
  int row0 = rb * 128, col0 = cb * 128, cbq = cb & 3;

  f32x4 zero4 = {0.f, 0.f, 0.f, 0.f};
  f32x4 acc[4][4];
#pragma unroll
  for (int i = 0; i < 4; ++i)
#pragma unroll
    for (int j = 0; j < 4; ++j) acc[i][j] = zero4;

  // staging: per tile 2 A + 2 B 16B-loads/thread. Slot s -> row s>>2, phys s&3;
  // logical col = phys ^ ((row>>1)&3)  (row-pair XOR; rows 64B).
  int ra = tid >> 2;                       // 0..63 (second half: +64, same XOR)
  int lcol = ((tid & 3) ^ ((ra >> 1) & 3)) * 8;
  const unsigned short* gA0 = A + (size_t)(row0 + ra) * 1024 + lcol;
  const unsigned short* gA1 = gA0 + (size_t)64 * 1024;
  const unsigned short* gB0 = BT + (size_t)(col0 + ra) * 1024 + lcol;
  const unsigned short* gB1 = gB0 + (size_t)64 * 1024;

  int fr = lane & 15, hi = lane >> 4;

#define E_STAGE(buf, kt)                                                     \
  {                                                                          \
    unsigned short* db = smem[buf];                                          \
    GLOAD_LDS16(gA0 + (kt), db + tid * 8);                                   \
    GLOAD_LDS16(gA1 + (kt), db + 2048 + tid * 8);                            \
    GLOAD_LDS16(gB0 + (kt), db + 4096 + tid * 8);                            \
    GLOAD_LDS16(gB1 + (kt), db + 6144 + tid * 8);                            \
  }

  E_STAGE(0, 0);

  for (int t = 0; t < 32; ++t) {
    if (t + 1 < 32) {
      E_STAGE((t + 1) & 1, (t + 1) << 5);
      asm volatile("s_waitcnt vmcnt(4)" ::: "memory");
    } else {
      asm volatile("s_waitcnt vmcnt(0)" ::: "memory");
    }
    __builtin_amdgcn_sched_barrier(0);
    __builtin_amdgcn_s_barrier();
    __builtin_amdgcn_sched_barrier(0);

    const unsigned short* As = smem[t & 1];
    const unsigned short* Bs = smem[t & 1] + 4096;
    bf16x8 af[4], bfr[4];
#pragma unroll
    for (int mi = 0; mi < 4; ++mi) {
      int rl = wr * 64 + mi * 16 + fr;
      af[mi] = *(const bf16x8*)&As[rl * 32 + (hi ^ ((rl >> 1) & 3)) * 8];
    }
#pragma unroll
    for (int ni = 0; ni < 4; ++ni) {
      int rl = wc * 64 + ni * 16 + fr;
      bfr[ni] = *(const bf16x8*)&Bs[rl * 32 + (hi ^ ((rl >> 1) & 3)) * 8];
    }
#pragma unroll
    for (int mi = 0; mi < 4; ++mi)
#pragma unroll
      for (int ni = 0; ni < 4; ++ni)
        acc[mi][ni] = __builtin_amdgcn_mfma_f32_16x16x32_bf16(af[mi], bfr[ni],
                                                              acc[mi][ni], 0, 0, 0);
    __builtin_amdgcn_sched_barrier(0);
    __builtin_amdgcn_s_barrier();
  }
#undef E_STAGE

  // ---- epilogue: h -> swizzled LDS (32KB = whole smem) -> W2 MFMA ----
  unsigned short* hsm = &smem[0][0];
  int cc = col0 >> 9;
  int dg0 = col0 & 511;
#pragma unroll
  for (int mi = 0; mi < 4; ++mi) {
#pragma unroll
    for (int j = 0; j < 4; ++j) {
      int rl = wr * 64 + hi * 4 + mi * 16 + j;
      const float* avp = avec + (size_t)(row0 + rl) * 512 + dg0;
      const float* bvp = bvec + (size_t)cc * 512 + dg0;
#pragma unroll
      for (int ni = 0; ni < 4; ++ni) {
        int cl = wc * 64 + ni * 16 + fr;
        float v = acc[mi][ni][j] + avp[cl] + bvp[cl];
        v = fmaxf(v, 0.f);
        int slot = cl >> 3;
        hsm[rl * 128 + (((slot ^ rl) & 7) << 3) + (slot & 8) * 8 + (cl & 7)] = f2b(v);
      }
    }
  }
  __syncthreads();
  f32x4 s0 = zero4, s1 = zero4;
  int r0l = wid * 32 + fr;
  int r1l = wid * 32 + 16 + fr;
#pragma unroll
  for (int kt2 = 0; kt2 < 4; ++kt2) {
    int slot = kt2 * 4 + hi;
    bf16x8 a0 = *(const bf16x8*)&hsm[r0l * 128 + (((slot ^ r0l) & 7) << 3) + (slot & 8) * 8];
    bf16x8 a1 = *(const bf16x8*)&hsm[r1l * 128 + (((slot ^ r1l) & 7) << 3) + (slot & 8) * 8];
    bf16x8 b = *(const bf16x8*)&w2t[(size_t)fr * 512 + dg0 + kt2 * 32 + hi * 8];
    s0 = __builtin_amdgcn_mfma_f32_16x16x32_bf16(a0, b, s0, 0, 0, 0);
    s1 = __builtin_amdgcn_mfma_f32_16x16x32_bf16(a1, b, s1, 0, 0, 0);
  }
  if (fr < 3) {
    float* sp = sPart + ((size_t)cbq * 2048 + row0) * 96 + cc * 3 + fr;
#pragma unroll
    for (int j = 0; j < 4; ++j) {
      sp[(size_t)(wid * 32 + hi * 4 + j) * 96] = s0[j];
      sp[(size_t)(wid * 32 + 16 + hi * 4 + j) * 96] = s1[j];
    }
  }
}

// ---------- fold 4 score slices + b2, then is_start/is_end (2 words/block) ----------
__global__ __launch_bounds__(256) void foldmask_k(const float* __restrict__ part,
    const float* __restrict__ b2, float* __restrict__ outS,
    int* __restrict__ is_s, int* __restrict__ is_e) {
  __shared__ float sc[192];
  int b = blockIdx.x;  // 1024 blocks x 192 elems = 196608
  int i = threadIdx.x;
  if (i < 192) {
    int idx = b * 192 + i;
    float s = b2[i % 3] + part[idx] + part[196608 + idx] +
              part[2 * 196608 + idx] + part[3 * 196608 + idx];
    outS[idx] = s;
    sc[i] = s;
  }
  __syncthreads();
  if (i < 2) {
    int s = 0, e = 0;
#pragma unroll
    for (int c = 0; c < 32; ++c) {
      s |= (sc[i * 96 + c * 3 + 0] >= 0.f);
      e |= (sc[i * 96 + c * 3 + 1] >= 0.f);
    }
    is_s[2 * b + i] = s;
    is_e[2 * b + i] = e;
  }
}

// ---------- fused span: 16 spans/wave, barrier-free, bf16 UV ----------
__global__ __launch_bounds__(256) void spanfuse_k(
    const unsigned short* __restrict__ UVb, const unsigned short* __restrict__ bsp1b,
    const unsigned short* __restrict__ MmTb, const float* __restrict__ cvv,
    const int* __restrict__ is_s, const int* __restrict__ is_e,
    float* __restrict__ outIdx, float* __restrict__ outMask,
    float* __restrict__ outLog) {
  __shared__ __align__(16) unsigned short Rs[4][16][32];
  int tid = threadIdx.x, lane = tid & 63, w = tid >> 6;
  int fr = lane & 15, hi = lane >> 4;
  int row = lane >> 2, q = lane & 3;
  int n = blockIdx.x * 64 + w * 16 + row;
  int wi = n / MAXW;
  int j = n - wi * MAXW;
  int er = wi + j;
  int valid = er < W_WORDS;
  int e = valid ? er : (W_WORDS - 1);
  int mask = (valid && is_s[wi] && is_e[e]) ? 1 : 0;
  if (q == 0) {
    outIdx[2 * n] = (float)wi;
    outIdx[2 * n + 1] = (float)e;
    outMask[n] = (float)mask;
  }
  int si = mask ? wi : 0, ei = mask ? e : 0;
  const unsigned short* Up = UVb + (size_t)si * 2048 + q * 8;
  const unsigned short* Vp = UVb + (size_t)ei * 2048 + 1024 + q * 8;
  const unsigned short* bp = bsp1b + q * 8;
  unsigned short* wRs = &Rs[w][0][0];
  f32x4 zero4 = {0.f, 0.f, 0.f, 0.f};
  f32x4 a0 = zero4, a1 = zero4;

  bf16x8 u = *(const bf16x8*)Up;
  bf16x8 v = *(const bf16x8*)Vp;
  bf16x8 bb = *(const bf16x8*)bp;
  bf16x8 fb0 = *(const bf16x8*)&MmTb[(size_t)fr * 1024 + hi * 8];
  bf16x8 fb1 = *(const bf16x8*)&MmTb[(size_t)(16 + fr) * 1024 + hi * 8];

  for (int kt = 0; kt < 32; ++kt) {
    int kn = ((kt + 1) & 31) * 32;
    bf16x8 un = *(const bf16x8*)(Up + kn);
    bf16x8 vn = *(const bf16x8*)(Vp + kn);
    bf16x8 bn = *(const bf16x8*)(bp + kn);
    bf16x8 f0n = *(const bf16x8*)&MmTb[(size_t)fr * 1024 + kn + hi * 8];
    bf16x8 f1n = *(const bf16x8*)&MmTb[(size_t)(16 + fr) * 1024 + kn + hi * 8];

    bf16x8 o;
#pragma unroll
    for (int i = 0; i < 8; ++i) {
      float s = b2f((unsigned short)u[i]) + b2f((unsigned short)v[i]) +
                b2f((unsigned short)bb[i]);
      o[i] = (short)f2b(fmaxf(s, 0.f));
    }
    *(bf16x8*)&wRs[row * 32 + (q ^ (row & 3)) * 8] = o;
    asm volatile("s_waitcnt lgkmcnt(0)" ::: "memory");
    bf16x8 fa = *(const bf16x8*)&wRs[fr * 32 + ((hi ^ (fr & 3)) & 3) * 8];
    a0 = __builtin_amdgcn_mfma_f32_16x16x32_bf16(fa, fb0, a0, 0, 0, 0);
    a1 = __builtin_amdgcn_mfma_f32_16x16x32_bf16(fa, fb1, a1, 0, 0, 0);
    u = un; v = vn; bb = bn; fb0 = f0n; fb1 = f1n;
  }

  int n0 = blockIdx.x * 64 + w * 16;
  float c0 = cvv[fr], c1 = cvv[16 + fr];
#pragma unroll
  for (int jj = 0; jj < 4; ++jj) {
    int nn = n0 + hi * 4 + jj;
    outLog[(size_t)nn * 32 + fr] = a0[jj] + c0;
    outLog[(size_t)nn * 32 + 16 + fr] = a1[jj] + c1;
  }
}

extern "C" void kernel_launch(void* const* d_in, const int* in_sizes, int n_in,
                              void* d_out, int out_size, void* d_ws, size_t ws_size,
                              hipStream_t stream) {
  const float* hs   = (const float*)d_in[0];
  const int*   wm   = (const int*)d_in[1];
  const float* L    = (const float*)d_in[2];
  const float* Wt   = (const float*)d_in[3];
  const float* bt   = (const float*)d_in[4];
  const float* Wl   = (const float*)d_in[5];
  const float* bl   = (const float*)d_in[6];
  const float* W1a  = (const float*)d_in[7];
  const float* W1b  = (const float*)d_in[8];
  const float* W1c  = (const float*)d_in[9];
  const float* b1   = (const float*)d_in[10];
  const float* W2   = (const float*)d_in[11];
  const float* b2   = (const float*)d_in[12];
  const float* Wsp1 = (const float*)d_in[13];
  const float* bsp1 = (const float*)d_in[14];
  const float* Wsp2 = (const float*)d_in[15];
  const float* bsp2 = (const float*)d_in[16];

  char* p = (char*)d_ws;
  auto alloc = [&p](size_t bytes) {
    char* r = p;
    p += (bytes + 255) & ~(size_t)255;
    return r;
  };
  unsigned short* we_b   = (unsigned short*)alloc((size_t)2048 * 1024 * 2);
  // WtT and Wsp1Tc MUST be adjacent: merged BT = [WtT ; Wsp1Tc] (4096 x 1024)
  unsigned short* WtT    = (unsigned short*)alloc((size_t)2048 * 1024 * 2);
  unsigned short* Wsp1Tc = (unsigned short*)alloc((size_t)2048 * 1024 * 2);
  unsigned short* t0b    = (unsigned short*)alloc((size_t)2048 * 1024 * 2);
  unsigned short* t1b    = (unsigned short*)alloc((size_t)2048 * 1024 * 2);
  float*          lab    = (float*)alloc((size_t)32 * 2048 * 4);
  unsigned short* W1aT   = (unsigned short*)alloc((size_t)512 * 1024 * 2);
  float*          Avec   = (float*)alloc((size_t)2048 * 512 * 4);
  float*          BvecB  = (float*)alloc((size_t)32 * 512 * 4);
  float*          W1cT   = (float*)alloc((size_t)512 * 1024 * 4);
  unsigned short* KmatT  = (unsigned short*)alloc((size_t)16384 * 1024 * 2);
  float*          sPart  = (float*)alloc((size_t)4 * 2048 * 96 * 4);
  int*            is_s   = (int*)alloc(2048 * 4);
  int*            is_e   = (int*)alloc(2048 * 4);
  unsigned short* UVb    = (unsigned short*)alloc((size_t)2048 * 2048 * 2);
  float*          Wsp2T  = (float*)alloc((size_t)1024 * 1024 * 4);
  float*          MmTf   = (float*)alloc((size_t)32 * 1024 * 4);
  unsigned short* MmTb   = (unsigned short*)alloc((size_t)32 * 1024 * 2);
  float*          cv     = (float*)alloc(32 * 4);
  unsigned short* W2padT = (unsigned short*)alloc((size_t)16 * 512 * 2);
  unsigned short* bsp1b  = (unsigned short*)alloc((size_t)1024 * 2);

  float* outS    = (float*)d_out;
  float* outIdx  = outS + (size_t)2048 * 32 * 3;
  float* outMask = outIdx + (size_t)NSPAN * 2;
  float* outLog  = outMask + NSPAN;

  // transposes + gather in one launch
  mega0_k<<<dim3(96, 32, 7), dim3(32, 8), 0, stream>>>(
      hs, wm, we_b, Wt, W1a, Wsp1, W1c, Wsp2, WtT, W1aT, Wsp1Tc, W1cT, Wsp2T);

  // lab = L@Wl+bl and MmTf = L@Wsp2T
  rgemm8z_k<<<dim3(128, 4, 2), 256, 0, stream>>>(L, Wl, bl, lab, Wsp2T, MmTf);

  // kmat + BvecB + misc in one launch
  mega1_k<<<8417, 256, 0, stream>>>(lab, W1cT, KmatT, W1b, b1, BvecB,
                                    bsp2, L, cv, MmTf, MmTb, W2, W2padT, bsp1, bsp1b);

  // merged: [tok | UV] = we @ [Wt | Wsp1^T-cat]  (N = 4096)
  gemm_k<1><<<dim3(32, 16), 256, 0, stream>>>(we_b, WtT, 4096, 1024, nullptr,
                                              t0b, t1b, UVb, bt);
  // Avec = t0 @ W1a  (2048 x 512 f32)
  gemm_k<0><<<dim3(4, 16), 256, 0, stream>>>(t0b, W1aT, 512, 1024, Avec,
                                             nullptr, nullptr, nullptr, nullptr);
  // E-GEMM (BK=32, 5 blocks/CU) + fused score partials
  egemm_k<<<2048, 256, 0, stream>>>(t1b, KmatT, Avec, BvecB, W2padT, sPart);

  // fold scores + masks
  foldmask_k<<<1024, 256, 0, stream>>>(sPart, b2, outS, is_s, is_e);

  // fused span: 16 spans/wave, barrier-free
  spanfuse_k<<<384, 256, 0, stream>>>(UVb, bsp1b, MmTb, cv, is_s, is_e,
                                      outIdx, outMask, outLog);
}

// Round 10
// 227.969 us; speedup vs baseline: 1.1719x; 1.1039x over previous
//
#include <hip/hip_runtime.h>
#include <hip/hip_bf16.h>

#define W_WORDS 2048
#define H_DIM   1024
#define C_LAB   32
#define HID_D   512
#define MAXW    12
#define NSPAN   (W_WORDS * MAXW)

typedef __attribute__((ext_vector_type(8))) short bf16x8;
typedef __attribute__((ext_vector_type(4))) float f32x4;

__device__ __forceinline__ unsigned short f2b(float x) {
  union { float f; unsigned int i; } v; v.f = x;
  unsigned int r = v.i + 0x7FFFu + ((v.i >> 16) & 1u);
  return (unsigned short)(r >> 16);
}
__device__ __forceinline__ float b2f(unsigned short b) {
  union { float f; unsigned int i; } v; v.i = ((unsigned int)b) << 16;
  return v.f;
}

#define GLOAD_LDS16(g, l)                                                    \
  __builtin_amdgcn_global_load_lds(                                          \
      (const __attribute__((address_space(1))) unsigned int*)(g),            \
      (__attribute__((address_space(3))) unsigned int*)(l), 16, 0, 0)

// ---------- mega0: 6 transposes (z<6) + gather (z==6) + Wtb0 cvt (z==7) ----------
__global__ void mega0_k(const float* __restrict__ hs, const int* __restrict__ wm,
    unsigned short* __restrict__ we_b,
    const float* __restrict__ Wt, const float* __restrict__ W1a,
    const float* __restrict__ Wsp1, const float* __restrict__ W1c,
    const float* __restrict__ Wsp2,
    unsigned short* __restrict__ WtT, unsigned short* __restrict__ W1aT,
    unsigned short* __restrict__ Wsp1Tc, float* __restrict__ W1cT,
    float* __restrict__ Wsp2T, unsigned short* __restrict__ Wtb0) {
  if (blockIdx.z == 6) {  // gather: we_b[m-1] = bf16(hs[t])
    int t = blockIdx.y * 96 + blockIdx.x;
    int m = wm[t];
    if (m <= 0) return;
    const float* src = hs + (size_t)t * H_DIM;
    unsigned short* dst = we_b + (size_t)(m - 1) * H_DIM;
    int i = (threadIdx.y * 32 + threadIdx.x) * 4;
    float4 v = *(const float4*)(src + i);
    *(ushort4*)(dst + i) = make_ushort4(f2b(v.x), f2b(v.y), f2b(v.z), f2b(v.w));
    return;
  }
  int c0 = blockIdx.x * 32, r0 = blockIdx.y * 32;
  if (blockIdx.z == 7) {  // Wtb0[h][g] = bf16(Wt[h][g]), g<1024
    if (c0 >= 1024) return;
    for (int i = threadIdx.y; i < 32; i += 8)
      Wtb0[(size_t)(r0 + i) * 1024 + c0 + threadIdx.x] =
          f2b(Wt[(size_t)(r0 + i) * 2048 + c0 + threadIdx.x]);
    return;
  }
  const float* in;
  void* out;
  int R, C, obf;
  switch (blockIdx.z) {
    case 0: in = Wt;   out = WtT;    R = 1024; C = 2048; obf = 1; break;
    case 1: in = W1a;  out = W1aT;   R = 1024; C = 512;  obf = 1; break;
    case 2: in = Wsp1; out = Wsp1Tc; R = 1024; C = 1024; obf = 1; break;
    case 3: in = Wsp1 + 1048576; out = Wsp1Tc + 1048576; R = 1024; C = 1024; obf = 1; break;
    case 4: in = W1c;  out = W1cT;   R = 1024; C = 512;  obf = 0; break;
    default: in = Wsp2; out = Wsp2T; R = 1024; C = 1024; obf = 0; break;
  }
  if (c0 >= C || r0 >= R) return;
  __shared__ float tile[32][33];
  for (int i = threadIdx.y; i < 32; i += 8)
    tile[i][threadIdx.x] = in[(size_t)(r0 + i) * C + c0 + threadIdx.x];
  __syncthreads();
  if (obf) {
    unsigned short* o = (unsigned short*)out;
    for (int i = threadIdx.y; i < 32; i += 8)
      o[(size_t)(c0 + i) * R + r0 + threadIdx.x] = f2b(tile[threadIdx.x][i]);
  } else {
    float* o = (float*)out;
    for (int i = threadIdx.y; i < 32; i += 8)
      o[(size_t)(c0 + i) * R + r0 + threadIdx.x] = tile[threadIdx.x][i];
  }
}

// ---------- small GEMM body, 8 A-rows per block ----------
__device__ __forceinline__ void rgemm8_body(int N, int M,
    const float* __restrict__ A, int lda, const float* __restrict__ B, int ldb,
    const float* __restrict__ bias, float* __restrict__ out, int ldc,
    int bx, int by, float* shf) {
  float (*Asm)[1024] = (float(*)[1024])shf;
  float (*red)[16][8] = (float(*)[16][8])(shf + 8192);
  int m0 = by * 8;
  for (int idx = threadIdx.x; idx < 8 * 1024; idx += 256) {
    int mm = idx >> 10, kk = idx & 1023;
    Asm[mm][kk] = (m0 + mm < M) ? A[(size_t)(m0 + mm) * lda + kk] : 0.f;
  }
  __syncthreads();
  int tx = threadIdx.x & 15, ty = threadIdx.x >> 4;
  int n = bx * 16 + tx;
  float acc[8] = {0.f, 0.f, 0.f, 0.f, 0.f, 0.f, 0.f, 0.f};
  if (n < N) {
    for (int k = ty * 64; k < ty * 64 + 64; ++k) {
      float bv = B[(size_t)k * ldb + n];
#pragma unroll
      for (int mm = 0; mm < 8; ++mm) acc[mm] = fmaf(Asm[mm][k], bv, acc[mm]);
    }
  }
#pragma unroll
  for (int mm = 0; mm < 8; ++mm) red[ty][tx][mm] = acc[mm];
  __syncthreads();
  if (ty < 8 && n < N && m0 + ty < M) {
    float s = 0.f;
#pragma unroll
    for (int q = 0; q < 16; ++q) s += red[q][tx][ty];
    if (bias) s += bias[n];
    out[(size_t)(m0 + ty) * ldc + n] = s;
  }
}

// lab = L@Wl+bl (z=0) and MmTf = L@Wsp2T (z=1)
__global__ __launch_bounds__(256) void rgemm8z_k(
    const float* __restrict__ L, const float* __restrict__ Wl,
    const float* __restrict__ bl, float* __restrict__ lab,
    const float* __restrict__ Wsp2T, float* __restrict__ MmTf) {
  __shared__ float shf[10240];
  if (blockIdx.z == 0) {
    rgemm8_body(2048, 32, L, 1024, Wl, 2048, bl, lab, 2048, blockIdx.x, blockIdx.y, shf);
  } else {
    if (blockIdx.x >= 64) return;
    rgemm8_body(1024, 32, L, 1024, Wsp2T, 1024, nullptr, MmTf, 1024,
                blockIdx.x, blockIdx.y, shf);
  }
}

// ---------- mega1: kmat + BvecB + misc + bt0A(K-parallel) ----------
__global__ __launch_bounds__(256) void mega1_k(
    const float* __restrict__ lab, const float* __restrict__ W1cT,
    unsigned short* __restrict__ KT,
    const float* __restrict__ W1b, const float* __restrict__ b1,
    float* __restrict__ BvecB,
    const float* __restrict__ bsp2, const float* __restrict__ L,
    float* __restrict__ cv, const float* __restrict__ MmTf,
    unsigned short* __restrict__ MmTb, const float* __restrict__ W2,
    unsigned short* __restrict__ W2padT, const float* __restrict__ bsp1,
    unsigned short* __restrict__ bsp1b,
    const float* __restrict__ bt, const float* __restrict__ W1a,
    float* __restrict__ bt0A) {
  __shared__ float shf[10240];
  int g = blockIdx.x;
  if (g < 8192) {  // KT[(c*512+d)][h] = l1[c][h] * W1c[h][d], 8 h/thread
    size_t gid = (size_t)g * 256 + threadIdx.x;
    int row = (int)(gid >> 7);
    int h0 = ((int)gid & 127) * 8;
    int c = row >> 9, d = row & 511;
    const float* lp = lab + (size_t)c * 2048 + 1024 + h0;
    const float* wp = W1cT + (size_t)d * 1024 + h0;
    float4 l0 = *(const float4*)lp, l1 = *(const float4*)(lp + 4);
    float4 w0 = *(const float4*)wp, w1 = *(const float4*)(wp + 4);
    bf16x8 o;
    o[0] = (short)f2b(l0.x * w0.x); o[1] = (short)f2b(l0.y * w0.y);
    o[2] = (short)f2b(l0.z * w0.z); o[3] = (short)f2b(l0.w * w0.w);
    o[4] = (short)f2b(l1.x * w1.x); o[5] = (short)f2b(l1.y * w1.y);
    o[6] = (short)f2b(l1.z * w1.z); o[7] = (short)f2b(l1.w * w1.w);
    *(bf16x8*)(KT + (size_t)row * 1024 + h0) = o;
  } else if (g < 8320) {  // BvecB = l0 @ W1b + b1   (32 x 512)
    int b = g - 8192;
    rgemm8_body(512, 32, lab, 2048, W1b, 512, b1, BvecB, 512, b & 31, b >> 5, shf);
  } else {
    int b = g - 8320;
    if (b < 32) {  // cv[c] = dot(bsp2, L[c])
      int c = b;
      float a = 0.f;
      for (int k = threadIdx.x; k < 1024; k += 256)
        a = fmaf(bsp2[k], L[(size_t)c * 1024 + k], a);
#pragma unroll
      for (int off = 32; off; off >>= 1) a += __shfl_down(a, off);
      if ((threadIdx.x & 63) == 0) shf[threadIdx.x >> 6] = a;
      __syncthreads();
      if (threadIdx.x == 0) cv[c] = shf[0] + shf[1] + shf[2] + shf[3];
    } else if (b < 64) {  // MmTf -> MmTb bf16
      int i = (b - 32) * 1024 + threadIdx.x * 4;
      float4 v = *(const float4*)(MmTf + i);
      *(ushort4*)(MmTb + i) = make_ushort4(f2b(v.x), f2b(v.y), f2b(v.z), f2b(v.w));
    } else if (b < 96) {  // W2padT[n][d] = n<3 ? W2[d][n] : 0
      int i = (b - 64) * 256 + threadIdx.x;
      int n = i >> 9, d = i & 511;
      W2padT[i] = f2b(n < 3 ? W2[d * 3 + n] : 0.f);
    } else if (b == 96) {  // bsp1 -> bsp1b bf16
      int i = threadIdx.x * 4;
      float4 v = *(const float4*)(bsp1 + i);
      *(ushort4*)(bsp1b + i) = make_ushort4(f2b(v.x), f2b(v.y), f2b(v.z), f2b(v.w));
    } else {  // b in [97,129): bt0A[d] = dot(bt[0:1024], W1a[:,d]), K-parallel
      float (*red)[16] = (float(*)[16])shf;
      int tx = threadIdx.x & 15, ty = threadIdx.x >> 4;
      int d = (b - 97) * 16 + tx;
      float a = 0.f;
      for (int k = ty * 64; k < ty * 64 + 64; ++k)
        a = fmaf(bt[k], W1a[(size_t)k * 512 + d], a);
      red[ty][tx] = a;
      __syncthreads();
      if (ty == 0) {
        float s = 0.f;
#pragma unroll
        for (int q = 0; q < 16; ++q) s += red[q][tx];
        bt0A[d] = s;
      }
    }
  }
}

// ---------- bf16 MFMA GEMM, 128x128 tile, BK=64, counted-vmcnt dbuf ----------
// MODE 1: merged N=4608: c<2048 tok(+bias)->out0/out1; <4096 -> out2 bf16 (UVb);
//         else Avec f32 = v + bias2[c-4096] -> outF (ld 512)
// MODE 3: out0 bf16 full tile (ld N)
template <int MODE>
__global__ __launch_bounds__(256) void gemm_k(
    const unsigned short* __restrict__ A, const unsigned short* __restrict__ BT,
    int N, int K,
    float* __restrict__ outF,
    unsigned short* __restrict__ out0, unsigned short* __restrict__ out1,
    unsigned short* __restrict__ out2,
    const float* __restrict__ bias, const float* __restrict__ bias2) {
  __shared__ __align__(16) unsigned short smem[2][16384];  // 64 KB dbuf
  int tid = threadIdx.x;
  int lane = tid & 63, wid = tid >> 6;
  int wr = wid >> 1, wc = wid & 1;
  int row0 = blockIdx.y * 128, col0 = blockIdx.x * 128;

  f32x4 zero4 = {0.f, 0.f, 0.f, 0.f};
  f32x4 acc[4][4];
#pragma unroll
  for (int i = 0; i < 4; ++i)
#pragma unroll
    for (int j = 0; j < 4; ++j) acc[i][j] = zero4;

  int srow = tid >> 3;
  int scol = ((tid & 7) ^ (srow & 7)) * 8;  // pre-swizzled global source
  const unsigned short* gA = A + (size_t)(row0 + srow) * K + scol;
  const unsigned short* gB = BT + (size_t)(col0 + srow) * K + scol;

  int fr = lane & 15, hi = lane >> 4;

#define G_STAGE(buf, kt)                                                     \
  {                                                                          \
    unsigned short* dA = smem[buf] + tid * 8;                                \
    unsigned short* dB = smem[buf] + 8192 + tid * 8;                         \
    _Pragma("unroll")                                                        \
    for (int i2 = 0; i2 < 4; ++i2) {                                         \
      GLOAD_LDS16(gA + (size_t)(i2 * 32) * K + (kt), dA + i2 * 2048);        \
      GLOAD_LDS16(gB + (size_t)(i2 * 32) * K + (kt), dB + i2 * 2048);        \
    }                                                                        \
  }

  G_STAGE(0, 0);

  int nt = K >> 6;
  for (int t = 0; t < nt; ++t) {
    if (t + 1 < nt) {
      G_STAGE((t + 1) & 1, (t + 1) << 6);
      asm volatile("s_waitcnt vmcnt(8)" ::: "memory");
    } else {
      asm volatile("s_waitcnt vmcnt(0)" ::: "memory");
    }
    __builtin_amdgcn_sched_barrier(0);
    __builtin_amdgcn_s_barrier();
    __builtin_amdgcn_sched_barrier(0);

    const unsigned short* As = smem[t & 1];
    const unsigned short* Bs = smem[t & 1] + 8192;
    bf16x8 af[4][2], bfr[4][2];
#pragma unroll
    for (int mi = 0; mi < 4; ++mi) {
      int rl = wr * 64 + mi * 16 + fr;
#pragma unroll
      for (int kk = 0; kk < 2; ++kk)
        af[mi][kk] = *(const bf16x8*)&As[rl * 64 + (((kk << 2) | hi) ^ (rl & 7)) * 8];
    }
#pragma unroll
    for (int ni = 0; ni < 4; ++ni) {
      int rl = wc * 64 + ni * 16 + fr;
#pragma unroll
      for (int kk = 0; kk < 2; ++kk)
        bfr[ni][kk] = *(const bf16x8*)&Bs[rl * 64 + (((kk << 2) | hi) ^ (rl & 7)) * 8];
    }
#pragma unroll
    for (int kk = 0; kk < 2; ++kk)
#pragma unroll
      for (int mi = 0; mi < 4; ++mi)
#pragma unroll
        for (int ni = 0; ni < 4; ++ni)
          acc[mi][ni] = __builtin_amdgcn_mfma_f32_16x16x32_bf16(af[mi][kk], bfr[ni][kk],
                                                                acc[mi][ni], 0, 0, 0);
    __builtin_amdgcn_sched_barrier(0);
    __builtin_amdgcn_s_barrier();
  }
#undef G_STAGE

  int rbase = row0 + wr * 64 + (hi << 2);
  int cbase = col0 + wc * 64 + fr;
#pragma unroll
  for (int mi = 0; mi < 4; ++mi) {
#pragma unroll
    for (int ni = 0; ni < 4; ++ni) {
      int ccol = cbase + ni * 16;
#pragma unroll
      for (int j = 0; j < 4; ++j) {
        int r = rbase + mi * 16 + j;
        float v = acc[mi][ni][j];
        if (MODE == 3) {
          out0[(size_t)r * N + ccol] = f2b(v);
        } else {
          if (ccol < 2048) {
            v += bias[ccol];
            if (ccol < 1024) out0[(size_t)r * 1024 + ccol] = f2b(v);
            else             out1[(size_t)r * 1024 + (ccol - 1024)] = f2b(v);
          } else if (ccol < 4096) {
            out2[(size_t)r * 2048 + (ccol - 2048)] = f2b(v);
          } else {
            outF[(size_t)r * 512 + (ccol - 4096)] = v + bias2[ccol - 4096];
          }
        }
      }
    }
  }
}

// ---------- E-GEMM: 128² tile, BK=64, counted-vmcnt dbuf, 8x8 supertile ----------
// h = relu(gemm + avec + bvec) -> swizzled LDS -> MFMA vs W2padT -> sPart slice.
__global__ __launch_bounds__(256) void egemm_k(
    const unsigned short* __restrict__ A,   // t1b [2048][1024]
    const unsigned short* __restrict__ BT,  // KmatT [16384][1024]
    const float* __restrict__ avec, const float* __restrict__ bvec,
    const unsigned short* __restrict__ w2t, float* __restrict__ sPart) {
  __shared__ __align__(16) unsigned short smem[2][16384];  // 64 KB dbuf
  int tid = threadIdx.x;
  int lane = tid & 63, wid = tid >> 6;
  int wr = wid >> 1, wc = wid & 1;
  // 8 xcd x (2x2 supergrid of 8rb x 8cb supertiles): L2 set = 2MB A + 2MB B
  int bid = blockIdx.x;
  int xcd = bid & 7, ii = bid >> 3;
  int sg = ii >> 6, inner = ii & 63;
  int rb = ((sg >> 1) << 3) | (inner & 7);
  int cb = xcd * 16 + (((sg & 1) << 3) | (inner >> 3));
  int row0 = rb * 128, col0 = cb * 128, cbq = cb & 3;

  f32x4 zero4 = {0.f, 0.f, 0.f, 0.f};
  f32x4 acc[4][4];
#pragma unroll
  for (int i = 0; i < 4; ++i)
#pragma unroll
    for (int j = 0; j < 4; ++j) acc[i][j] = zero4;

  int srow = tid >> 3;
  int scol = ((tid & 7) ^ (srow & 7)) * 8;
  const unsigned short* gA = A + (size_t)(row0 + srow) * 1024 + scol;
  const unsigned short* gB = BT + (size_t)(col0 + srow) * 1024 + scol;

  int fr = lane & 15, hi = lane >> 4;

#define E_STAGE(buf, kt)                                                     \
  {                                                                          \
    unsigned short* dA = smem[buf] + tid * 8;                                \
    unsigned short* dB = smem[buf] + 8192 + tid * 8;                         \
    _Pragma("unroll")                                                        \
    for (int i2 = 0; i2 < 4; ++i2) {                                         \
      GLOAD_LDS16(gA + (size_t)(i2 * 32) * 1024 + (kt), dA + i2 * 2048);     \
      GLOAD_LDS16(gB + (size_t)(i2 * 32) * 1024 + (kt), dB + i2 * 2048);     \
    }                                                                        \
  }

  E_STAGE(0, 0);

  for (int t = 0; t < 16; ++t) {
    if (t + 1 < 16) {
      E_STAGE((t + 1) & 1, (t + 1) << 6);
      asm volatile("s_waitcnt vmcnt(8)" ::: "memory");
    } else {
      asm volatile("s_waitcnt vmcnt(0)" ::: "memory");
    }
    __builtin_amdgcn_sched_barrier(0);
    __builtin_amdgcn_s_barrier();
    __builtin_amdgcn_sched_barrier(0);

    const unsigned short* As = smem[t & 1];
    const unsigned short* Bs = smem[t & 1] + 8192;
    bf16x8 af[4][2], bfr[4][2];
#pragma unroll
    for (int mi = 0; mi < 4; ++mi) {
      int rl = wr * 64 + mi * 16 + fr;
#pragma unroll
      for (int kk = 0; kk < 2; ++kk)
        af[mi][kk] = *(const bf16x8*)&As[rl * 64 + (((kk << 2) | hi) ^ (rl & 7)) * 8];
    }
#pragma unroll
    for (int ni = 0; ni < 4; ++ni) {
      int rl = wc * 64 + ni * 16 + fr;
#pragma unroll
      for (int kk = 0; kk < 2; ++kk)
        bfr[ni][kk] = *(const bf16x8*)&Bs[rl * 64 + (((kk << 2) | hi) ^ (rl & 7)) * 8];
    }
#pragma unroll
    for (int kk = 0; kk < 2; ++kk)
#pragma unroll
      for (int mi = 0; mi < 4; ++mi)
#pragma unroll
        for (int ni = 0; ni < 4; ++ni)
          acc[mi][ni] = __builtin_amdgcn_mfma_f32_16x16x32_bf16(af[mi][kk], bfr[ni][kk],
                                                                acc[mi][ni], 0, 0, 0);
    __builtin_amdgcn_sched_barrier(0);
    __builtin_amdgcn_s_barrier();
  }
#undef E_STAGE

  // ---- epilogue: h -> swizzled LDS (32 KB of smem[0]) -> W2 MFMA ----
  unsigned short* hsm = &smem[0][0];
  int cc = col0 >> 9;
  int dg0 = col0 & 511;
#pragma unroll
  for (int mi = 0; mi < 4; ++mi) {
#pragma unroll
    for (int j = 0; j < 4; ++j) {
      int rl = wr * 64 + hi * 4 + mi * 16 + j;
      const float* avp = avec + (size_t)(row0 + rl) * 512 + dg0;
      const float* bvp = bvec + (size_t)cc * 512 + dg0;
#pragma unroll
      for (int ni = 0; ni < 4; ++ni) {
        int cl = wc * 64 + ni * 16 + fr;
        float v = acc[mi][ni][j] + avp[cl] + bvp[cl];
        v = fmaxf(v, 0.f);
        int slot = cl >> 3;
        hsm[rl * 128 + (((slot ^ rl) & 7) << 3) + (slot & 8) * 8 + (cl & 7)] = f2b(v);
      }
    }
  }
  __syncthreads();
  f32x4 s0 = zero4, s1 = zero4;
  int r0l = wid * 32 + fr;
  int r1l = wid * 32 + 16 + fr;
#pragma unroll
  for (int kt2 = 0; kt2 < 4; ++kt2) {
    int slot = kt2 * 4 + hi;
    bf16x8 a0 = *(const bf16x8*)&hsm[r0l * 128 + (((slot ^ r0l) & 7) << 3) + (slot & 8) * 8];
    bf16x8 a1 = *(const bf16x8*)&hsm[r1l * 128 + (((slot ^ r1l) & 7) << 3) + (slot & 8) * 8];
    bf16x8 b = *(const bf16x8*)&w2t[(size_t)fr * 512 + dg0 + kt2 * 32 + hi * 8];
    s0 = __builtin_amdgcn_mfma_f32_16x16x32_bf16(a0, b, s0, 0, 0, 0);
    s1 = __builtin_amdgcn_mfma_f32_16x16x32_bf16(a1, b, s1, 0, 0, 0);
  }
  if (fr < 3) {
    float* sp = sPart + ((size_t)cbq * 2048 + row0) * 96 + cc * 3 + fr;
#pragma unroll
    for (int j = 0; j < 4; ++j) {
      sp[(size_t)(wid * 32 + hi * 4 + j) * 96] = s0[j];
      sp[(size_t)(wid * 32 + 16 + hi * 4 + j) * 96] = s1[j];
    }
  }
}

// ---------- fold 4 score slices + b2, then is_start/is_end ----------
__global__ __launch_bounds__(256) void foldmask_k(const float* __restrict__ part,
    const float* __restrict__ b2, float* __restrict__ outS,
    int* __restrict__ is_s, int* __restrict__ is_e) {
  __shared__ float sc[192];
  int b = blockIdx.x;
  int i = threadIdx.x;
  if (i < 192) {
    int idx = b * 192 + i;
    float s = b2[i % 3] + part[idx] + part[196608 + idx] +
              part[2 * 196608 + idx] + part[3 * 196608 + idx];
    outS[idx] = s;
    sc[i] = s;
  }
  __syncthreads();
  if (i < 2) {
    int s = 0, e = 0;
#pragma unroll
    for (int c = 0; c < 32; ++c) {
      s |= (sc[i * 96 + c * 3 + 0] >= 0.f);
      e |= (sc[i * 96 + c * 3 + 1] >= 0.f);
    }
    is_s[2 * b + i] = s;
    is_e[2 * b + i] = e;
  }
}

// ---------- fused span: 16 spans/wave, barrier-free, bf16 UV ----------
__global__ __launch_bounds__(256) void spanfuse_k(
    const unsigned short* __restrict__ UVb, const unsigned short* __restrict__ bsp1b,
    const unsigned short* __restrict__ MmTb, const float* __restrict__ cvv,
    const int* __restrict__ is_s, const int* __restrict__ is_e,
    float* __restrict__ outIdx, float* __restrict__ outMask,
    float* __restrict__ outLog) {
  __shared__ __align__(16) unsigned short Rs[4][16][32];
  int tid = threadIdx.x, lane = tid & 63, w = tid >> 6;
  int fr = lane & 15, hi = lane >> 4;
  int row = lane >> 2, q = lane & 3;
  int n = blockIdx.x * 64 + w * 16 + row;
  int wi = n / MAXW;
  int j = n - wi * MAXW;
  int er = wi + j;
  int valid = er < W_WORDS;
  int e = valid ? er : (W_WORDS - 1);
  int mask = (valid && is_s[wi] && is_e[e]) ? 1 : 0;
  if (q == 0) {
    outIdx[2 * n] = (float)wi;
    outIdx[2 * n + 1] = (float)e;
    outMask[n] = (float)mask;
  }
  int si = mask ? wi : 0, ei = mask ? e : 0;
  const unsigned short* Up = UVb + (size_t)si * 2048 + q * 8;
  const unsigned short* Vp = UVb + (size_t)ei * 2048 + 1024 + q * 8;
  const unsigned short* bp = bsp1b + q * 8;
  unsigned short* wRs = &Rs[w][0][0];
  f32x4 zero4 = {0.f, 0.f, 0.f, 0.f};
  f32x4 a0 = zero4, a1 = zero4;

  bf16x8 u = *(const bf16x8*)Up;
  bf16x8 v = *(const bf16x8*)Vp;
  bf16x8 bb = *(const bf16x8*)bp;
  bf16x8 fb0 = *(const bf16x8*)&MmTb[(size_t)fr * 1024 + hi * 8];
  bf16x8 fb1 = *(const bf16x8*)&MmTb[(size_t)(16 + fr) * 1024 + hi * 8];

  for (int kt = 0; kt < 32; ++kt) {
    int kn = ((kt + 1) & 31) * 32;
    bf16x8 un = *(const bf16x8*)(Up + kn);
    bf16x8 vn = *(const bf16x8*)(Vp + kn);
    bf16x8 bn = *(const bf16x8*)(bp + kn);
    bf16x8 f0n = *(const bf16x8*)&MmTb[(size_t)fr * 1024 + kn + hi * 8];
    bf16x8 f1n = *(const bf16x8*)&MmTb[(size_t)(16 + fr) * 1024 + kn + hi * 8];

    bf16x8 o;
#pragma unroll
    for (int i = 0; i < 8; ++i) {
      float s = b2f((unsigned short)u[i]) + b2f((unsigned short)v[i]) +
                b2f((unsigned short)bb[i]);
      o[i] = (short)f2b(fmaxf(s, 0.f));
    }
    *(bf16x8*)&wRs[row * 32 + (q ^ (row & 3)) * 8] = o;
    asm volatile("s_waitcnt lgkmcnt(0)" ::: "memory");
    bf16x8 fa = *(const bf16x8*)&wRs[fr * 32 + ((hi ^ (fr & 3)) & 3) * 8];
    a0 = __builtin_amdgcn_mfma_f32_16x16x32_bf16(fa, fb0, a0, 0, 0, 0);
    a1 = __builtin_amdgcn_mfma_f32_16x16x32_bf16(fa, fb1, a1, 0, 0, 0);
    u = un; v = vn; bb = bn; fb0 = f0n; fb1 = f1n;
  }

  int n0 = blockIdx.x * 64 + w * 16;
  float c0 = cvv[fr], c1 = cvv[16 + fr];
#pragma unroll
  for (int jj = 0; jj < 4; ++jj) {
    int nn = n0 + hi * 4 + jj;
    outLog[(size_t)nn * 32 + fr] = a0[jj] + c0;
    outLog[(size_t)nn * 32 + 16 + fr] = a1[jj] + c1;
  }
}

extern "C" void kernel_launch(void* const* d_in, const int* in_sizes, int n_in,
                              void* d_out, int out_size, void* d_ws, size_t ws_size,
                              hipStream_t stream) {
  const float* hs   = (const float*)d_in[0];
  const int*   wm   = (const int*)d_in[1];
  const float* L    = (const float*)d_in[2];
  const float* Wt   = (const float*)d_in[3];
  const float* bt   = (const float*)d_in[4];
  const float* Wl   = (const float*)d_in[5];
  const float* bl   = (const float*)d_in[6];
  const float* W1a  = (const float*)d_in[7];
  const float* W1b  = (const float*)d_in[8];
  const float* W1c  = (const float*)d_in[9];
  const float* b1   = (const float*)d_in[10];
  const float* W2   = (const float*)d_in[11];
  const float* b2   = (const float*)d_in[12];
  const float* Wsp1 = (const float*)d_in[13];
  const float* bsp1 = (const float*)d_in[14];
  const float* Wsp2 = (const float*)d_in[15];
  const float* bsp2 = (const float*)d_in[16];

  char* p = (char*)d_ws;
  auto alloc = [&p](size_t bytes) {
    char* r = p;
    p += (bytes + 255) & ~(size_t)255;
    return r;
  };
  unsigned short* we_b   = (unsigned short*)alloc((size_t)2048 * 1024 * 2);
  // WtT, Wsp1Tc, WfuseT MUST be adjacent: merged BT (4608 x 1024)
  unsigned short* WtT    = (unsigned short*)alloc((size_t)2048 * 1024 * 2);
  unsigned short* Wsp1Tc = (unsigned short*)alloc((size_t)2048 * 1024 * 2);
  unsigned short* WfuseT = (unsigned short*)alloc((size_t)512 * 1024 * 2);
  unsigned short* t0b    = (unsigned short*)alloc((size_t)2048 * 1024 * 2);
  unsigned short* t1b    = (unsigned short*)alloc((size_t)2048 * 1024 * 2);
  float*          lab    = (float*)alloc((size_t)32 * 2048 * 4);
  unsigned short* W1aT   = (unsigned short*)alloc((size_t)512 * 1024 * 2);
  unsigned short* Wtb0   = (unsigned short*)alloc((size_t)1024 * 1024 * 2);
  float*          Avec   = (float*)alloc((size_t)2048 * 512 * 4);
  float*          BvecB  = (float*)alloc((size_t)32 * 512 * 4);
  float*          bt0A   = (float*)alloc(512 * 4);
  float*          W1cT   = (float*)alloc((size_t)512 * 1024 * 4);
  unsigned short* KmatT  = (unsigned short*)alloc((size_t)16384 * 1024 * 2);
  float*          sPart  = (float*)alloc((size_t)4 * 2048 * 96 * 4);
  int*            is_s   = (int*)alloc(2048 * 4);
  int*            is_e   = (int*)alloc(2048 * 4);
  unsigned short* UVb    = (unsigned short*)alloc((size_t)2048 * 2048 * 2);
  float*          Wsp2T  = (float*)alloc((size_t)1024 * 1024 * 4);
  float*          MmTf   = (float*)alloc((size_t)32 * 1024 * 4);
  unsigned short* MmTb   = (unsigned short*)alloc((size_t)32 * 1024 * 2);
  float*          cv     = (float*)alloc(32 * 4);
  unsigned short* W2padT = (unsigned short*)alloc((size_t)16 * 512 * 2);
  unsigned short* bsp1b  = (unsigned short*)alloc((size_t)1024 * 2);

  float* outS    = (float*)d_out;
  float* outIdx  = outS + (size_t)2048 * 32 * 3;
  float* outMask = outIdx + (size_t)NSPAN * 2;
  float* outLog  = outMask + NSPAN;

  // transposes + gather + Wtb0 in one launch
  mega0_k<<<dim3(96, 32, 8), dim3(32, 8), 0, stream>>>(
      hs, wm, we_b, Wt, W1a, Wsp1, W1c, Wsp2, WtT, W1aT, Wsp1Tc, W1cT, Wsp2T, Wtb0);

  // lab = L@Wl+bl and MmTf = L@Wsp2T
  rgemm8z_k<<<dim3(128, 4, 2), 256, 0, stream>>>(L, Wl, bl, lab, Wsp2T, MmTf);

  // kmat + BvecB + misc + bt0A in one launch
  mega1_k<<<8449, 256, 0, stream>>>(lab, W1cT, KmatT, W1b, b1, BvecB,
                                    bsp2, L, cv, MmTf, MmTb, W2, W2padT, bsp1, bsp1b,
                                    bt, W1a, bt0A);

  // WfuseT = W1aT @ Wtb0^T  (512 x 1024 bf16): Avec folding matrix
  gemm_k<3><<<dim3(8, 4), 256, 0, stream>>>(W1aT, Wtb0, 1024, 1024, nullptr, WfuseT,
                                            nullptr, nullptr, nullptr, nullptr);
  // merged: [tok | UV | Avec] = we @ [Wt | Wsp1 | Wfuse]  (N = 4608)
  gemm_k<1><<<dim3(36, 16), 256, 0, stream>>>(we_b, WtT, 4608, 1024, Avec, t0b, t1b,
                                              UVb, bt, bt0A);
  // E-GEMM (BK=64, counted vmcnt, 8x8 supertile) + fused score partials
  egemm_k<<<2048, 256, 0, stream>>>(t1b, KmatT, Avec, BvecB, W2padT, sPart);

  // fold scores + masks
  foldmask_k<<<1024, 256, 0, stream>>>(sPart, b2, outS, is_s, is_e);

  // fused span: 16 spans/wave, barrier-free
  spanfuse_k<<<384, 256, 0, stream>>>(UVb, bsp1b, MmTb, cv, is_s, is_e,
                                      outIdx, outMask, outLog);
}